// Round 4
// baseline (647.097 us; speedup 1.0000x reference)
//
#include <hip/hip_runtime.h>
#include <hip/hip_bf16.h>

#define LOG2E 1.4426950408889634f
#define LN2   0.6931471805599453f

typedef __attribute__((ext_vector_type(8))) short short8;
typedef __attribute__((ext_vector_type(4))) float f32x4;

#define B_ 8
#define N_ 128
#define M_ 32
#define C_ 65536
#define KCHUNKS 128
#define KC (C_ / KCHUNKS)   // 512
#define BST (KC + 8)        // gt LDS stride in bf16 elems: bank-step 4 -> 2-way max (free)

__device__ __forceinline__ unsigned short f2bf(float f) {
  unsigned u = __builtin_bit_cast(unsigned, f);
  u += 0x7fffu + ((u >> 16) & 1u);   // RNE
  return (unsigned short)(u >> 16);
}

// grid 1024 = (128 k-chunks x 8 batches), 256 threads. Wave g handles pred rows
// 32g..32g+31 (both x- and s-GEMM). gt KC-slice staged to LDS as bf16 ONCE;
// K-loop is barrier-free: A-fragments built directly in registers from global.
__global__ __launch_bounds__(256, 4) void cost_partial_kernel(
    const float* __restrict__ pred, const float* __restrict__ gt,
    float* __restrict__ xg_part, float* __restrict__ sg_part,
    float* __restrict__ sp_part, float* __restrict__ ss_part,
    float* __restrict__ gts_part)
{
  __shared__ unsigned short Bt[M_ * BST];
  const int kc = blockIdx.x, b = blockIdx.y;
  const int tid = threadIdx.x;
  const int g = tid >> 6, lane = tid & 63;
  const int quad = lane >> 4, lcol = lane & 15;
  const int slab = kc * B_ + b;
  const int c0 = kc * KC;

  // ---- stage gt KC-slice -> bf16 LDS (coalesced: 8 threads/row) + row sums
  {
    const int row = tid >> 3, gh = tid & 7;          // 32 rows x 8 threads
    const float* gp = gt + (size_t)b * M_ * C_ + (size_t)row * C_ + c0 + gh * 64;
    float ga = 0.f;
#pragma unroll
    for (int i = 0; i < 16; ++i) {
      float4 v = *(const float4*)(gp + i * 4);
      ga += v.x + v.y + v.z + v.w;
      unsigned lo = (__builtin_bit_cast(unsigned, v.y) & 0xFFFF0000u) |
                    (__builtin_bit_cast(unsigned, v.x) >> 16);
      unsigned hi = (__builtin_bit_cast(unsigned, v.w) & 0xFFFF0000u) |
                    (__builtin_bit_cast(unsigned, v.z) >> 16);
      *(uint2*)&Bt[row * BST + gh * 64 + i * 4] = (uint2){lo, hi};
    }
    ga += __shfl_xor(ga, 1);
    ga += __shfl_xor(ga, 2);
    ga += __shfl_xor(ga, 4);
    if (gh == 0) gts_part[slab * M_ + row] = ga;
  }
  __syncthreads();

  // ---- barrier-free K-loop
  const float* pA = pred + (size_t)b * N_ * C_ + (size_t)(g * 32) * C_ + c0;
  const float* rowp0 = pA + (size_t)lcol * C_;         // rt=0 row
  const float* rowp1 = pA + (size_t)(16 + lcol) * C_;  // rt=1 row

  f32x4 ax[2][2], as_[2][2];
#pragma unroll
  for (int rt = 0; rt < 2; ++rt)
#pragma unroll
    for (int ct = 0; ct < 2; ++ct) {
      ax[rt][ct] = (f32x4){0.f, 0.f, 0.f, 0.f};
      as_[rt][ct] = (f32x4){0.f, 0.f, 0.f, 0.f};
    }
  float sp0 = 0.f, sp1 = 0.f, ss0 = 0.f, ss1 = 0.f;

  for (int ks = 0; ks < KC; ks += 32) {
    const int kq = ks + quad * 8;
    float4 a0 = *(const float4*)(rowp0 + kq);
    float4 a1 = *(const float4*)(rowp0 + kq + 4);
    float4 a2 = *(const float4*)(rowp1 + kq);
    float4 a3 = *(const float4*)(rowp1 + kq + 4);

    short8 xf0, sf0, xf1, sf1;
    {
      float xs[8] = {a0.x, a0.y, a0.z, a0.w, a1.x, a1.y, a1.z, a1.w};
#pragma unroll
      for (int e = 0; e < 8; ++e) {
        float x = xs[e];
        float t = fminf(fmaxf(x * LOG2E, -80.f), 80.f);
        float e2 = __builtin_amdgcn_exp2f(t);
        float z = 1.f + e2;
        float s = e2 * __builtin_amdgcn_rcpf(z);
        sp0 += __builtin_amdgcn_logf(z) * LN2;
        ss0 += s;
        xf0[e] = (short)f2bf(x);
        sf0[e] = (short)f2bf(s);
      }
    }
    {
      float xs[8] = {a2.x, a2.y, a2.z, a2.w, a3.x, a3.y, a3.z, a3.w};
#pragma unroll
      for (int e = 0; e < 8; ++e) {
        float x = xs[e];
        float t = fminf(fmaxf(x * LOG2E, -80.f), 80.f);
        float e2 = __builtin_amdgcn_exp2f(t);
        float z = 1.f + e2;
        float s = e2 * __builtin_amdgcn_rcpf(z);
        sp1 += __builtin_amdgcn_logf(z) * LN2;
        ss1 += s;
        xf1[e] = (short)f2bf(x);
        sf1[e] = (short)f2bf(s);
      }
    }

    short8 b0 = *(const short8*)&Bt[lcol * BST + kq];
    short8 b1 = *(const short8*)&Bt[(16 + lcol) * BST + kq];

    ax[0][0] = __builtin_amdgcn_mfma_f32_16x16x32_bf16(xf0, b0, ax[0][0], 0, 0, 0);
    ax[0][1] = __builtin_amdgcn_mfma_f32_16x16x32_bf16(xf0, b1, ax[0][1], 0, 0, 0);
    ax[1][0] = __builtin_amdgcn_mfma_f32_16x16x32_bf16(xf1, b0, ax[1][0], 0, 0, 0);
    ax[1][1] = __builtin_amdgcn_mfma_f32_16x16x32_bf16(xf1, b1, ax[1][1], 0, 0, 0);
    as_[0][0] = __builtin_amdgcn_mfma_f32_16x16x32_bf16(sf0, b0, as_[0][0], 0, 0, 0);
    as_[0][1] = __builtin_amdgcn_mfma_f32_16x16x32_bf16(sf0, b1, as_[0][1], 0, 0, 0);
    as_[1][0] = __builtin_amdgcn_mfma_f32_16x16x32_bf16(sf1, b0, as_[1][0], 0, 0, 0);
    as_[1][1] = __builtin_amdgcn_mfma_f32_16x16x32_bf16(sf1, b1, as_[1][1], 0, 0, 0);
  }

  // row sums: lanes {m, m+16, m+32, m+48} hold quad-partials of row m
  sp0 += __shfl_xor(sp0, 16); sp0 += __shfl_xor(sp0, 32);
  sp1 += __shfl_xor(sp1, 16); sp1 += __shfl_xor(sp1, 32);
  ss0 += __shfl_xor(ss0, 16); ss0 += __shfl_xor(ss0, 32);
  ss1 += __shfl_xor(ss1, 16); ss1 += __shfl_xor(ss1, 32);
  if (quad == 0) {
    const int r0 = g * 32 + lcol;
    sp_part[slab * N_ + r0] = sp0;      sp_part[slab * N_ + r0 + 16] = sp1;
    ss_part[slab * N_ + r0] = ss0;      ss_part[slab * N_ + r0 + 16] = ss1;
  }

  // GEMM partials: C/D layout col=lane&15, row=quad*4+reg
#pragma unroll
  for (int rt = 0; rt < 2; ++rt)
#pragma unroll
    for (int ct = 0; ct < 2; ++ct)
#pragma unroll
      for (int reg = 0; reg < 4; ++reg) {
        const int r = g * 32 + rt * 16 + quad * 4 + reg;
        const int c = ct * 16 + lcol;
        xg_part[((size_t)slab * N_ + r) * M_ + c] = ax[rt][ct][reg];
        sg_part[((size_t)slab * N_ + r) * M_ + c] = as_[rt][ct][reg];
      }
}

__global__ void finalize_kernel(const float* __restrict__ obj,
    const float* __restrict__ xg_part, const float* __restrict__ sg_part,
    const float* __restrict__ sp_part, const float* __restrict__ ss_part,
    const float* __restrict__ gts_part, float* __restrict__ cost)
{
  int idx = blockIdx.x * blockDim.x + threadIdx.x;  // [0, 32768)
  int b = idx >> 12;
  int n = (idx >> 5) & 127;
  int m = idx & 31;
  float xa = 0.f, sa = 0.f, spa = 0.f, ssa = 0.f, ga = 0.f;
#pragma unroll 8
  for (int kc = 0; kc < KCHUNKS; ++kc) {
    int slab = kc * B_ + b;
    xa  += xg_part[((size_t)slab * N_ + n) * M_ + m];
    sa  += sg_part[((size_t)slab * N_ + n) * M_ + m];
    spa += sp_part[slab * N_ + n];
    ssa += ss_part[slab * N_ + n];
    ga  += gts_part[slab * M_ + m];
  }
  float o = obj[b * N_ + n];
  float t = fminf(fmaxf(o * LOG2E, -80.f), 80.f);
  float e2 = __builtin_amdgcn_exp2f(t);
  float sig = e2 * __builtin_amdgcn_rcpf(1.f + e2);
  float bce = (spa - xa) * (1.0f / (float)C_);
  float dice = 1.f - (2.f * sa + 1.f) / (ssa + ga + 1.f);
  cost[idx] = -2.f * sig + 5.f * bce + 5.f * dice;
}

#define BIGF 1e30f

// full-wave min via DPP (6 VALU ops), result broadcast via readlane(63)
__device__ __forceinline__ float wave_min_all(float x) {
  const int BI = __builtin_bit_cast(int, BIGF);
  int v = __builtin_bit_cast(int, x);
#define MIN_STEP(ctrl)                                                        \
  {                                                                           \
    int t_ = __builtin_amdgcn_update_dpp(BI, v, ctrl, 0xf, 0xf, false);       \
    v = __builtin_bit_cast(int, fminf(__builtin_bit_cast(float, v),           \
                                      __builtin_bit_cast(float, t_)));        \
  }
  MIN_STEP(0x111)  // row_shr:1
  MIN_STEP(0x112)  // row_shr:2
  MIN_STEP(0x114)  // row_shr:4
  MIN_STEP(0x118)  // row_shr:8
  MIN_STEP(0x142)  // row_bcast:15
  MIN_STEP(0x143)  // row_bcast:31
#undef MIN_STEP
  return __builtin_bit_cast(float, __builtin_amdgcn_readlane(v, 63));
}

__device__ __forceinline__ float rdlane_f(float x, int l) {
  return __builtin_bit_cast(float, __builtin_amdgcn_readlane(__builtin_bit_cast(int, x), l));
}

// JV LSAP on cost^T [32 x 128], one wave per batch. Lane owns cols 2*lane, 2*lane+1.
// All state in registers; cost in LDS (stride 129 = conflict-free).
__global__ __launch_bounds__(64) void lsap_kernel(const float* __restrict__ cost,
                                                  float* __restrict__ out)
{
  const int b = blockIdx.x;
  const int lane = threadIdx.x;
  __shared__ float cTs[M_ * 129];

#pragma unroll 4
  for (int t = 0; t < 16; ++t) {
    int e = t * 256 + lane * 4;
    float4 v4 = *(const float4*)&cost[b * 4096 + e];
    int n = e >> 5, m = e & 31;
    cTs[(m + 0) * 129 + n] = v4.x;
    cTs[(m + 1) * 129 + n] = v4.y;
    cTs[(m + 2) * 129 + n] = v4.z;
    cTs[(m + 3) * 129 + n] = v4.w;
  }
  __syncthreads();

  float u_reg = 0.f;      // u[lane], lane<32
  int c4r = -1;           // col4row[lane], lane<32
  float v0 = 0.f, v1 = 0.f;   // v[2*lane], v[2*lane+1]
  int r40 = -1, r41 = -1;     // row4col

  for (int cur = 0; cur < M_; ++cur) {
    float sh0 = BIGF, sh1 = BIGF;
    int p0 = -1, p1 = -1;
    bool sc0 = false, sc1 = false;
    unsigned srmask = 0u;
    int i = cur, sink = -1;
    float minVal = 0.f;

    while (sink < 0) {
      srmask |= 1u << i;
      float ui = rdlane_f(u_reg, i);
      float cc0 = cTs[i * 129 + 2 * lane];
      float cc1 = cTs[i * 129 + 2 * lane + 1];
      // match jnp associativity: ((minVal + c) - u[i]) - v
      float d0 = ((minVal + cc0) - ui) - v0;
      float d1 = ((minVal + cc1) - ui) - v1;
      if (!sc0 && d0 < sh0) { sh0 = d0; p0 = i; }
      if (!sc1 && d1 < sh1) { sh1 = d1; p1 = i; }
      float m0 = sc0 ? BIGF : sh0;
      float m1 = sc1 ? BIGF : sh1;
      float mv = wave_min_all(fminf(m0, m1));
      unsigned long long bl0 = __ballot(m0 == mv);
      unsigned long long bl1 = __ballot(m1 == mv);
      int j0 = bl0 ? 2 * (int)__builtin_ctzll(bl0) : 0x7fffffff;
      int j1 = bl1 ? 2 * (int)__builtin_ctzll(bl1) + 1 : 0x7fffffff;
      int j = j0 < j1 ? j0 : j1;   // first-index tie-break
      minVal = mv;
      if (lane == (j >> 1)) { if (j & 1) sc1 = true; else sc0 = true; }
      int nxt = __builtin_amdgcn_readlane((j & 1) ? r41 : r40, j >> 1);
      if (nxt < 0) sink = j; else i = nxt;
    }

    // dual updates (before augmentation, scipy order)
    int jj = c4r < 0 ? 0 : c4r;
    float g0 = __shfl(sh0, jj >> 1);
    float g1 = __shfl(sh1, jj >> 1);
    float sj = (jj & 1) ? g1 : g0;
    if (lane < M_) {
      if (lane == cur) u_reg += minVal;
      else if ((srmask >> lane) & 1u) u_reg += minVal - sj;
    }
    if (sc0) v0 -= minVal - sh0;
    if (sc1) v1 -= minVal - sh1;

    // augment along path
    int j = sink;
    while (true) {
      int i2 = __builtin_amdgcn_readlane((j & 1) ? p1 : p0, j >> 1);
      if (lane == (j >> 1)) { if (j & 1) r41 = i2; else r40 = i2; }
      int tmp = __builtin_amdgcn_readlane(c4r, i2);
      if (lane == i2) c4r = j;
      if (i2 == cur) break;
      j = tmp;
    }
  }
  if (lane < M_) out[b * M_ + lane] = (float)c4r;
}

extern "C" void kernel_launch(void* const* d_in, const int* in_sizes, int n_in,
                              void* d_out, int out_size, void* d_ws, size_t ws_size,
                              hipStream_t stream)
{
  const float* obj  = (const float*)d_in[0];   // [8,128]
  const float* pred = (const float*)d_in[1];   // [8,128,65536]
  const float* gt   = (const float*)d_in[2];   // [8,32,65536]
  float* out = (float*)d_out;                  // cost 32768 || indices 256 (as float)

  // per-(kc,b) partial slabs — no atomics, no memset needed
  float* xg_part  = (float*)d_ws;                              // 128*8*128*32
  float* sg_part  = xg_part + (size_t)KCHUNKS * B_ * N_ * M_;
  float* sp_part  = sg_part + (size_t)KCHUNKS * B_ * N_ * M_;  // 128*8*128
  float* ss_part  = sp_part + (size_t)KCHUNKS * B_ * N_;
  float* gts_part = ss_part + (size_t)KCHUNKS * B_ * N_;       // 128*8*32

  cost_partial_kernel<<<dim3(KCHUNKS, B_), 256, 0, stream>>>(
      pred, gt, xg_part, sg_part, sp_part, ss_part, gts_part);
  finalize_kernel<<<dim3(32768 / 256), 256, 0, stream>>>(
      obj, xg_part, sg_part, sp_part, ss_part, gts_part, out);
  lsap_kernel<<<dim3(B_), 64, 0, stream>>>(out, out + 32768);
}

// Round 5
// 644.647 us; speedup vs baseline: 1.0038x; 1.0038x over previous
//
#include <hip/hip_runtime.h>
#include <hip/hip_bf16.h>

#define LOG2E 1.4426950408889634f
#define LN2   0.6931471805599453f

typedef __attribute__((ext_vector_type(8))) short short8;
typedef __attribute__((ext_vector_type(4))) float f32x4;

#define B_ 8
#define N_ 128
#define M_ 32
#define C_ 65536
#define KCHUNKS 128
#define KC (C_ / KCHUNKS)   // 512
#define BK 64
#define AST 72              // LDS row stride in bf16 elems (144B: 16B-aligned, 2-way max)

__device__ __forceinline__ unsigned short f2bf(float f) {
  unsigned u = __builtin_bit_cast(unsigned, f);
  u += 0x7fffu + ((u >> 16) & 1u);   // RNE
  return (unsigned short)(u >> 16);
}
__device__ __forceinline__ unsigned pack_rne(float lo, float hi) {
  return (unsigned)f2bf(lo) | ((unsigned)f2bf(hi) << 16);
}
__device__ __forceinline__ unsigned pack_trunc(float lo, float hi) {  // exact for {0,1}
  unsigned ul = __builtin_bit_cast(unsigned, lo);
  unsigned uh = __builtin_bit_cast(unsigned, hi);
  return (uh & 0xFFFF0000u) | (ul >> 16);
}
__device__ __forceinline__ float bf2f(short h) {
  return __builtin_bit_cast(float, ((unsigned)(unsigned short)h) << 16);
}

// 1024 blocks (128 k-chunks x 8 batches) x 256 threads, 4 blocks/CU.
// Coalesced global->LDS staging of x-tile (bf16) + gt tile; s-fragment is
// recomputed from bf16 x at MFMA-read time (halves LDS -> 4 blocks/CU).
__global__ __launch_bounds__(256, 4) void cost_partial_kernel(
    const float* __restrict__ pred, const float* __restrict__ gt,
    float* __restrict__ xg_part, float* __restrict__ sg_part,
    float* __restrict__ sp_part, float* __restrict__ ss_part,
    float* __restrict__ gts_part)
{
  __shared__ unsigned short As[N_ * AST];   // x-tile, 18.4 KB
  __shared__ unsigned short Bt[M_ * AST];   // gt tile, 4.6 KB
  const int kc = blockIdx.x, b = blockIdx.y;
  const int tid = threadIdx.x;
  const int grp = tid >> 4, gl = tid & 15;   // pred staging: 16 rows/pass, 16 thr/row
  const int grow = tid >> 3, gh = tid & 7;   // gt staging: 32 rows, 8 thr/row
  const int g = tid >> 6, lane = tid & 63;
  const int quad = lane >> 4, lcol = lane & 15;
  const int slab = kc * B_ + b;
  const int c0 = kc * KC;

  const float* predB = pred + (size_t)b * N_ * C_ + c0;
  const float* gtB   = gt   + (size_t)b * M_ * C_ + (size_t)grow * C_ + c0;

  float spr[8], sr[8], gtacc = 0.f;
#pragma unroll
  for (int r = 0; r < 8; ++r) { spr[r] = 0.f; sr[r] = 0.f; }

  f32x4 ax[2][2], as_[2][2];
#pragma unroll
  for (int rt = 0; rt < 2; ++rt)
#pragma unroll
    for (int ct = 0; ct < 2; ++ct) {
      ax[rt][ct]  = (f32x4){0.f, 0.f, 0.f, 0.f};
      as_[rt][ct] = (f32x4){0.f, 0.f, 0.f, 0.f};
    }

  for (int ks = 0; ks < KC / BK; ++ks) {
    const int cb = ks * BK;
    float4 p[8];
#pragma unroll
    for (int r = 0; r < 8; ++r)
      p[r] = *(const float4*)(predB + (size_t)(r * 16 + grp) * C_ + cb + gl * 4);
    float4 g0 = *(const float4*)(gtB + cb + gh * 4);
    float4 g1 = *(const float4*)(gtB + cb + (gh + 8) * 4);

#pragma unroll
    for (int r = 0; r < 8; ++r) {
      const int row = r * 16 + grp;
      float xs[4] = {p[r].x, p[r].y, p[r].z, p[r].w};
#pragma unroll
      for (int e = 0; e < 4; ++e) {
        float x = xs[e];
        float t = fminf(fmaxf(x * LOG2E, -80.f), 80.f);
        float e2 = __builtin_amdgcn_exp2f(t);
        float z = 1.f + e2;
        spr[r] += __builtin_amdgcn_logf(z) * LN2;   // log1p(exp(x))
        sr[r]  += e2 * __builtin_amdgcn_rcpf(z);
      }
      *(uint2*)&As[row * AST + gl * 4] =
          (uint2){pack_rne(xs[0], xs[1]), pack_rne(xs[2], xs[3])};
    }
    gtacc += g0.x + g0.y + g0.z + g0.w + g1.x + g1.y + g1.z + g1.w;
    *(uint2*)&Bt[grow * AST + gh * 4] =
        (uint2){pack_trunc(g0.x, g0.y), pack_trunc(g0.z, g0.w)};
    *(uint2*)&Bt[grow * AST + (gh + 8) * 4] =
        (uint2){pack_trunc(g1.x, g1.y), pack_trunc(g1.z, g1.w)};
    __syncthreads();

#pragma unroll
    for (int k0 = 0; k0 < BK; k0 += 32) {
      const int koff = k0 + quad * 8;
      short8 b0 = *(const short8*)&Bt[lcol * AST + koff];
      short8 b1 = *(const short8*)&Bt[(16 + lcol) * AST + koff];
#pragma unroll
      for (int rt = 0; rt < 2; ++rt) {
        short8 xf = *(const short8*)&As[(g * 32 + rt * 16 + lcol) * AST + koff];
        short8 sf;
#pragma unroll
        for (int e = 0; e < 8; ++e) {
          float x = bf2f(xf[e]);
          float t = fminf(fmaxf(x * LOG2E, -80.f), 80.f);
          float e2 = __builtin_amdgcn_exp2f(t);
          sf[e] = (short)f2bf(e2 * __builtin_amdgcn_rcpf(1.f + e2));
        }
        ax[rt][0]  = __builtin_amdgcn_mfma_f32_16x16x32_bf16(xf, b0, ax[rt][0], 0, 0, 0);
        ax[rt][1]  = __builtin_amdgcn_mfma_f32_16x16x32_bf16(xf, b1, ax[rt][1], 0, 0, 0);
        as_[rt][0] = __builtin_amdgcn_mfma_f32_16x16x32_bf16(sf, b0, as_[rt][0], 0, 0, 0);
        as_[rt][1] = __builtin_amdgcn_mfma_f32_16x16x32_bf16(sf, b1, as_[rt][1], 0, 0, 0);
      }
    }
    __syncthreads();
  }

  // per-row sums: 16 consecutive lanes (gl) share a pred row
#pragma unroll
  for (int r = 0; r < 8; ++r) {
    float v1 = spr[r], v2 = sr[r];
#pragma unroll
    for (int off = 1; off < 16; off <<= 1) {
      v1 += __shfl_xor(v1, off);
      v2 += __shfl_xor(v2, off);
    }
    if (gl == 0) {
      sp_part[slab * N_ + r * 16 + grp] = v1;
      ss_part[slab * N_ + r * 16 + grp] = v2;
    }
  }
  gtacc += __shfl_xor(gtacc, 1);
  gtacc += __shfl_xor(gtacc, 2);
  gtacc += __shfl_xor(gtacc, 4);
  if (gh == 0) gts_part[slab * M_ + grow] = gtacc;

  // GEMM partials: C/D layout col=lane&15, row=quad*4+reg; wave g owns rows 32g..
#pragma unroll
  for (int rt = 0; rt < 2; ++rt)
#pragma unroll
    for (int ct = 0; ct < 2; ++ct)
#pragma unroll
      for (int reg = 0; reg < 4; ++reg) {
        const int r = g * 32 + rt * 16 + quad * 4 + reg;
        const int c = ct * 16 + lcol;
        xg_part[((size_t)slab * N_ + r) * M_ + c] = ax[rt][ct][reg];
        sg_part[((size_t)slab * N_ + r) * M_ + c] = as_[rt][ct][reg];
      }
}

__global__ void finalize_kernel(const float* __restrict__ obj,
    const float* __restrict__ xg_part, const float* __restrict__ sg_part,
    const float* __restrict__ sp_part, const float* __restrict__ ss_part,
    const float* __restrict__ gts_part, float* __restrict__ cost)
{
  int idx = blockIdx.x * blockDim.x + threadIdx.x;  // [0, 32768)
  int b = idx >> 12;
  int n = (idx >> 5) & 127;
  int m = idx & 31;
  float xa = 0.f, sa = 0.f, spa = 0.f, ssa = 0.f, ga = 0.f;
#pragma unroll 8
  for (int kc = 0; kc < KCHUNKS; ++kc) {
    int slab = kc * B_ + b;
    xa  += xg_part[((size_t)slab * N_ + n) * M_ + m];
    sa  += sg_part[((size_t)slab * N_ + n) * M_ + m];
    spa += sp_part[slab * N_ + n];
    ssa += ss_part[slab * N_ + n];
    ga  += gts_part[slab * M_ + m];
  }
  float o = obj[b * N_ + n];
  float t = fminf(fmaxf(o * LOG2E, -80.f), 80.f);
  float e2 = __builtin_amdgcn_exp2f(t);
  float sig = e2 * __builtin_amdgcn_rcpf(1.f + e2);
  float bce = (spa - xa) * (1.0f / (float)C_);
  float dice = 1.f - (2.f * sa + 1.f) / (ssa + ga + 1.f);
  cost[idx] = -2.f * sig + 5.f * bce + 5.f * dice;
}

#define BIGF 1e30f

// full-wave min via DPP (6 VALU ops), result broadcast via readlane(63)
__device__ __forceinline__ float wave_min_all(float x) {
  const int BI = __builtin_bit_cast(int, BIGF);
  int v = __builtin_bit_cast(int, x);
#define MIN_STEP(ctrl)                                                        \
  {                                                                           \
    int t_ = __builtin_amdgcn_update_dpp(BI, v, ctrl, 0xf, 0xf, false);       \
    v = __builtin_bit_cast(int, fminf(__builtin_bit_cast(float, v),           \
                                      __builtin_bit_cast(float, t_)));        \
  }
  MIN_STEP(0x111)  // row_shr:1
  MIN_STEP(0x112)  // row_shr:2
  MIN_STEP(0x114)  // row_shr:4
  MIN_STEP(0x118)  // row_shr:8
  MIN_STEP(0x142)  // row_bcast:15
  MIN_STEP(0x143)  // row_bcast:31
#undef MIN_STEP
  return __builtin_bit_cast(float, __builtin_amdgcn_readlane(v, 63));
}

__device__ __forceinline__ float rdlane_f(float x, int l) {
  return __builtin_bit_cast(float, __builtin_amdgcn_readlane(__builtin_bit_cast(int, x), l));
}

// JV LSAP on cost^T [32 x 128], one wave per batch. Lane owns cols 2*lane, 2*lane+1.
// All state in registers; cost in LDS (stride 129 = conflict-free).
__global__ __launch_bounds__(64) void lsap_kernel(const float* __restrict__ cost,
                                                  float* __restrict__ out)
{
  const int b = blockIdx.x;
  const int lane = threadIdx.x;
  __shared__ float cTs[M_ * 129];

#pragma unroll 4
  for (int t = 0; t < 16; ++t) {
    int e = t * 256 + lane * 4;
    float4 v4 = *(const float4*)&cost[b * 4096 + e];
    int n = e >> 5, m = e & 31;
    cTs[(m + 0) * 129 + n] = v4.x;
    cTs[(m + 1) * 129 + n] = v4.y;
    cTs[(m + 2) * 129 + n] = v4.z;
    cTs[(m + 3) * 129 + n] = v4.w;
  }
  __syncthreads();

  float u_reg = 0.f;      // u[lane], lane<32
  int c4r = -1;           // col4row[lane], lane<32
  float v0 = 0.f, v1 = 0.f;   // v[2*lane], v[2*lane+1]
  int r40 = -1, r41 = -1;     // row4col

  for (int cur = 0; cur < M_; ++cur) {
    float sh0 = BIGF, sh1 = BIGF;
    int p0 = -1, p1 = -1;
    bool sc0 = false, sc1 = false;
    unsigned srmask = 0u;
    int i = cur, sink = -1;
    float minVal = 0.f;

    while (sink < 0) {
      srmask |= 1u << i;
      float ui = rdlane_f(u_reg, i);
      float cc0 = cTs[i * 129 + 2 * lane];
      float cc1 = cTs[i * 129 + 2 * lane + 1];
      // match jnp associativity: ((minVal + c) - u[i]) - v
      float d0 = ((minVal + cc0) - ui) - v0;
      float d1 = ((minVal + cc1) - ui) - v1;
      if (!sc0 && d0 < sh0) { sh0 = d0; p0 = i; }
      if (!sc1 && d1 < sh1) { sh1 = d1; p1 = i; }
      float m0 = sc0 ? BIGF : sh0;
      float m1 = sc1 ? BIGF : sh1;
      float mv = wave_min_all(fminf(m0, m1));
      unsigned long long bl0 = __ballot(m0 == mv);
      unsigned long long bl1 = __ballot(m1 == mv);
      int j0 = bl0 ? 2 * (int)__builtin_ctzll(bl0) : 0x7fffffff;
      int j1 = bl1 ? 2 * (int)__builtin_ctzll(bl1) + 1 : 0x7fffffff;
      int j = j0 < j1 ? j0 : j1;   // first-index tie-break
      minVal = mv;
      if (lane == (j >> 1)) { if (j & 1) sc1 = true; else sc0 = true; }
      int nxt = __builtin_amdgcn_readlane((j & 1) ? r41 : r40, j >> 1);
      if (nxt < 0) sink = j; else i = nxt;
    }

    // dual updates (before augmentation, scipy order)
    int jj = c4r < 0 ? 0 : c4r;
    float g0 = __shfl(sh0, jj >> 1);
    float g1 = __shfl(sh1, jj >> 1);
    float sj = (jj & 1) ? g1 : g0;
    if (lane < M_) {
      if (lane == cur) u_reg += minVal;
      else if ((srmask >> lane) & 1u) u_reg += minVal - sj;
    }
    if (sc0) v0 -= minVal - sh0;
    if (sc1) v1 -= minVal - sh1;

    // augment along path
    int j = sink;
    while (true) {
      int i2 = __builtin_amdgcn_readlane((j & 1) ? p1 : p0, j >> 1);
      if (lane == (j >> 1)) { if (j & 1) r41 = i2; else r40 = i2; }
      int tmp = __builtin_amdgcn_readlane(c4r, i2);
      if (lane == i2) c4r = j;
      if (i2 == cur) break;
      j = tmp;
    }
  }
  if (lane < M_) out[b * M_ + lane] = (float)c4r;
}

extern "C" void kernel_launch(void* const* d_in, const int* in_sizes, int n_in,
                              void* d_out, int out_size, void* d_ws, size_t ws_size,
                              hipStream_t stream)
{
  const float* obj  = (const float*)d_in[0];   // [8,128]
  const float* pred = (const float*)d_in[1];   // [8,128,65536]
  const float* gt   = (const float*)d_in[2];   // [8,32,65536]
  float* out = (float*)d_out;                  // cost 32768 || indices 256 (as float)

  // per-(kc,b) partial slabs — no atomics, no memset needed
  float* xg_part  = (float*)d_ws;                              // 128*8*128*32
  float* sg_part  = xg_part + (size_t)KCHUNKS * B_ * N_ * M_;
  float* sp_part  = sg_part + (size_t)KCHUNKS * B_ * N_ * M_;  // 128*8*128
  float* ss_part  = sp_part + (size_t)KCHUNKS * B_ * N_;
  float* gts_part = ss_part + (size_t)KCHUNKS * B_ * N_;       // 128*8*32

  cost_partial_kernel<<<dim3(KCHUNKS, B_), 256, 0, stream>>>(
      pred, gt, xg_part, sg_part, sp_part, ss_part, gts_part);
  finalize_kernel<<<dim3(32768 / 256), 256, 0, stream>>>(
      obj, xg_part, sg_part, sp_part, ss_part, gts_part, out);
  lsap_kernel<<<dim3(B_), 64, 0, stream>>>(out, out + 32768);
}

// Round 6
// 575.036 us; speedup vs baseline: 1.1253x; 1.1211x over previous
//
#include <hip/hip_runtime.h>
#include <hip/hip_bf16.h>

#define LOG2E 1.4426950408889634f
#define LN2   0.6931471805599453f

typedef __attribute__((ext_vector_type(8))) short short8;
typedef __attribute__((ext_vector_type(4))) float f32x4;

#define B_ 8
#define N_ 128
#define M_ 32
#define C_ 65536
#define KCHUNKS 32
#define KC (C_ / KCHUNKS)   // 2048
#define BK 64
#define NK (KC / BK)        // 32
#define AST 72              // LDS row stride in bf16 elems (144B)

__device__ __forceinline__ unsigned short f2bf(float f) {
  unsigned u = __builtin_bit_cast(unsigned, f);
  u += 0x7fffu + ((u >> 16) & 1u);   // RNE
  return (unsigned short)(u >> 16);
}
__device__ __forceinline__ unsigned pack_rne(float lo, float hi) {
  return (unsigned)f2bf(lo) | ((unsigned)f2bf(hi) << 16);
}
__device__ __forceinline__ unsigned pack_trunc(float lo, float hi) {  // exact for {0,1}
  unsigned ul = __builtin_bit_cast(unsigned, lo);
  unsigned uh = __builtin_bit_cast(unsigned, hi);
  return (uh & 0xFFFF0000u) | (ul >> 16);
}

// grid = (32 kchunks, 4 row-tiles, 8 batches) = 1024 blocks x 256 thr, 4 blocks/CU.
// 32-pred-row tile. LDS double-buffered (x, s, gt tiles); register prefetch of the
// next K-tile overlaps global latency with MFMA + transcendentals; 1 barrier/iter.
// Waves 0,1 -> x-GEMM row halves; waves 2,3 -> s-GEMM row halves.
__global__ __launch_bounds__(256, 4) void cost_partial_kernel(
    const float* __restrict__ pred, const float* __restrict__ gt,
    float* __restrict__ xg_part, float* __restrict__ sg_part,
    float* __restrict__ sp_part, float* __restrict__ ss_part,
    float* __restrict__ gts_part)
{
  __shared__ unsigned short Asx[2][32 * AST];
  __shared__ unsigned short Ass[2][32 * AST];
  __shared__ unsigned short Btb[2][32 * AST];
  const int kc = blockIdx.x, rt = blockIdx.y, b = blockIdx.z;
  const int tid = threadIdx.x;
  const int strow = tid >> 3, h = tid & 7;   // staging: 32 rows x 8 thr
  const int wave = tid >> 6, lane = tid & 63;
  const int quad = lane >> 4, lcol = lane & 15;
  const int mat = wave >> 1;                 // 0 = x-GEMM, 1 = s-GEMM
  const int rhalf = (wave & 1) * 16;
  const int slab = kc * B_ + b;
  const int c0 = kc * KC;

  const float* predRow = pred + ((size_t)b * N_ + rt * 32 + strow) * C_ + c0 + h * 4;
  const float* gtRow   = gt + ((size_t)b * M_ + strow) * C_ + c0 + h * 4;

  float spacc = 0.f, ssacc = 0.f, gtacc = 0.f;
  f32x4 acc[2];
  acc[0] = (f32x4){0.f, 0.f, 0.f, 0.f};
  acc[1] = (f32x4){0.f, 0.f, 0.f, 0.f};

  float4 pp0, pp1, gg0, gg1;

#define LOADK(ks_)                                              \
  {                                                             \
    const float* pr_ = predRow + (ks_) * BK;                    \
    const float* gr_ = gtRow + (ks_) * BK;                      \
    pp0 = *(const float4*)(pr_);                                \
    pp1 = *(const float4*)(pr_ + 32);                           \
    gg0 = *(const float4*)(gr_);                                \
    gg1 = *(const float4*)(gr_ + 32);                           \
  }

#define STAGE(buf_)                                                           \
  {                                                                           \
    float xs_[8] = {pp0.x, pp0.y, pp0.z, pp0.w, pp1.x, pp1.y, pp1.z, pp1.w};  \
    float ss_[8];                                                             \
    _Pragma("unroll") for (int e = 0; e < 8; ++e) {                           \
      float x_ = xs_[e];                                                      \
      float t_ = fminf(fmaxf(x_ * LOG2E, -80.f), 80.f);                       \
      float e2_ = __builtin_amdgcn_exp2f(t_);                                 \
      float z_ = 1.f + e2_;                                                   \
      float s_ = e2_ * __builtin_amdgcn_rcpf(z_);                             \
      spacc += __builtin_amdgcn_logf(z_) * LN2;                               \
      ssacc += s_;                                                            \
      ss_[e] = s_;                                                            \
    }                                                                         \
    *(uint2*)&Asx[buf_][strow * AST + h * 4] =                                \
        (uint2){pack_rne(xs_[0], xs_[1]), pack_rne(xs_[2], xs_[3])};          \
    *(uint2*)&Asx[buf_][strow * AST + h * 4 + 32] =                           \
        (uint2){pack_rne(xs_[4], xs_[5]), pack_rne(xs_[6], xs_[7])};          \
    *(uint2*)&Ass[buf_][strow * AST + h * 4] =                                \
        (uint2){pack_rne(ss_[0], ss_[1]), pack_rne(ss_[2], ss_[3])};          \
    *(uint2*)&Ass[buf_][strow * AST + h * 4 + 32] =                           \
        (uint2){pack_rne(ss_[4], ss_[5]), pack_rne(ss_[6], ss_[7])};          \
    gtacc += gg0.x + gg0.y + gg0.z + gg0.w + gg1.x + gg1.y + gg1.z + gg1.w;   \
    *(uint2*)&Btb[buf_][strow * AST + h * 4] =                                \
        (uint2){pack_trunc(gg0.x, gg0.y), pack_trunc(gg0.z, gg0.w)};          \
    *(uint2*)&Btb[buf_][strow * AST + h * 4 + 32] =                           \
        (uint2){pack_trunc(gg1.x, gg1.y), pack_trunc(gg1.z, gg1.w)};          \
  }

  LOADK(0)
  STAGE(0)

  int cur = 0;
  for (int ks = 0; ks < NK; ++ks) {
    __syncthreads();
    const bool more = (ks + 1 < NK);
    if (more) LOADK(ks + 1)

    const unsigned short* Af =
        (mat ? &Ass[cur][0] : &Asx[cur][0]) + (rhalf + lcol) * AST;
    const unsigned short* Bf = &Btb[cur][0];
#pragma unroll
    for (int k0 = 0; k0 < BK; k0 += 32) {
      const int koff = k0 + quad * 8;
      short8 av = *(const short8*)&Af[koff];
      short8 b0 = *(const short8*)&Bf[lcol * AST + koff];
      short8 b1 = *(const short8*)&Bf[(16 + lcol) * AST + koff];
      acc[0] = __builtin_amdgcn_mfma_f32_16x16x32_bf16(av, b0, acc[0], 0, 0, 0);
      acc[1] = __builtin_amdgcn_mfma_f32_16x16x32_bf16(av, b1, acc[1], 0, 0, 0);
    }
    if (more) STAGE(cur ^ 1)
    cur ^= 1;
  }
#undef LOADK
#undef STAGE

  // pred row sums: 8 consecutive lanes (h) share a row
  spacc += __shfl_xor(spacc, 1);
  spacc += __shfl_xor(spacc, 2);
  spacc += __shfl_xor(spacc, 4);
  ssacc += __shfl_xor(ssacc, 1);
  ssacc += __shfl_xor(ssacc, 2);
  ssacc += __shfl_xor(ssacc, 4);
  if (h == 0) {
    sp_part[slab * N_ + rt * 32 + strow] = spacc;
    ss_part[slab * N_ + rt * 32 + strow] = ssacc;
  }
  if (rt == 0) {
    gtacc += __shfl_xor(gtacc, 1);
    gtacc += __shfl_xor(gtacc, 2);
    gtacc += __shfl_xor(gtacc, 4);
    if (h == 0) gts_part[slab * M_ + strow] = gtacc;
  }

  // GEMM partials: C/D layout col=lane&15, row=quad*4+reg
  float* dst = mat ? sg_part : xg_part;
#pragma unroll
  for (int ct = 0; ct < 2; ++ct)
#pragma unroll
    for (int reg = 0; reg < 4; ++reg) {
      const int r = rt * 32 + rhalf + quad * 4 + reg;
      dst[((size_t)slab * N_ + r) * M_ + ct * 16 + lcol] = acc[ct][reg];
    }
}

__global__ __launch_bounds__(128) void finalize_kernel(const float* __restrict__ obj,
    const float* __restrict__ xg_part, const float* __restrict__ sg_part,
    const float* __restrict__ sp_part, const float* __restrict__ ss_part,
    const float* __restrict__ gts_part, float* __restrict__ cost)
{
  int idx = blockIdx.x * 128 + threadIdx.x;  // [0, 32768)
  int b = idx >> 12;
  int n = (idx >> 5) & 127;
  int m = idx & 31;
  float xa = 0.f, sa = 0.f, spa = 0.f, ssa = 0.f, ga = 0.f;
#pragma unroll 8
  for (int kc = 0; kc < KCHUNKS; ++kc) {
    int slab = kc * B_ + b;
    xa  += xg_part[((size_t)slab * N_ + n) * M_ + m];
    sa  += sg_part[((size_t)slab * N_ + n) * M_ + m];
    spa += sp_part[slab * N_ + n];
    ssa += ss_part[slab * N_ + n];
    ga  += gts_part[slab * M_ + m];
  }
  float o = obj[b * N_ + n];
  float t = fminf(fmaxf(o * LOG2E, -80.f), 80.f);
  float e2 = __builtin_amdgcn_exp2f(t);
  float sig = e2 * __builtin_amdgcn_rcpf(1.f + e2);
  float bce = (spa - xa) * (1.0f / (float)C_);
  float dice = 1.f - (2.f * sa + 1.f) / (ssa + ga + 1.f);
  cost[idx] = -2.f * sig + 5.f * bce + 5.f * dice;
}

#define BIGF 1e30f

// full-wave min via DPP (6 VALU ops), result broadcast via readlane(63)
__device__ __forceinline__ float wave_min_all(float x) {
  const int BI = __builtin_bit_cast(int, BIGF);
  int v = __builtin_bit_cast(int, x);
#define MIN_STEP(ctrl)                                                        \
  {                                                                           \
    int t_ = __builtin_amdgcn_update_dpp(BI, v, ctrl, 0xf, 0xf, false);       \
    v = __builtin_bit_cast(int, fminf(__builtin_bit_cast(float, v),           \
                                      __builtin_bit_cast(float, t_)));        \
  }
  MIN_STEP(0x111)  // row_shr:1
  MIN_STEP(0x112)  // row_shr:2
  MIN_STEP(0x114)  // row_shr:4
  MIN_STEP(0x118)  // row_shr:8
  MIN_STEP(0x142)  // row_bcast:15
  MIN_STEP(0x143)  // row_bcast:31
#undef MIN_STEP
  return __builtin_bit_cast(float, __builtin_amdgcn_readlane(v, 63));
}

__device__ __forceinline__ float rdlane_f(float x, int l) {
  return __builtin_bit_cast(float, __builtin_amdgcn_readlane(__builtin_bit_cast(int, x), l));
}

// JV LSAP on cost^T [32 x 128], one wave per batch. Lane owns cols 2*lane, 2*lane+1.
// All state in registers; cost in LDS (stride 129 = conflict-free).
__global__ __launch_bounds__(64) void lsap_kernel(const float* __restrict__ cost,
                                                  float* __restrict__ out)
{
  const int b = blockIdx.x;
  const int lane = threadIdx.x;
  __shared__ float cTs[M_ * 129];

#pragma unroll 4
  for (int t = 0; t < 16; ++t) {
    int e = t * 256 + lane * 4;
    float4 v4 = *(const float4*)&cost[b * 4096 + e];
    int n = e >> 5, m = e & 31;
    cTs[(m + 0) * 129 + n] = v4.x;
    cTs[(m + 1) * 129 + n] = v4.y;
    cTs[(m + 2) * 129 + n] = v4.z;
    cTs[(m + 3) * 129 + n] = v4.w;
  }
  __syncthreads();

  float u_reg = 0.f;      // u[lane], lane<32
  int c4r = -1;           // col4row[lane], lane<32
  float v0 = 0.f, v1 = 0.f;   // v[2*lane], v[2*lane+1]
  int r40 = -1, r41 = -1;     // row4col

  for (int cur = 0; cur < M_; ++cur) {
    float sh0 = BIGF, sh1 = BIGF;
    int p0 = -1, p1 = -1;
    bool sc0 = false, sc1 = false;
    unsigned srmask = 0u;
    int i = cur, sink = -1;
    float minVal = 0.f;

    while (sink < 0) {
      srmask |= 1u << i;
      float ui = rdlane_f(u_reg, i);
      float cc0 = cTs[i * 129 + 2 * lane];
      float cc1 = cTs[i * 129 + 2 * lane + 1];
      // match jnp associativity: ((minVal + c) - u[i]) - v
      float d0 = ((minVal + cc0) - ui) - v0;
      float d1 = ((minVal + cc1) - ui) - v1;
      if (!sc0 && d0 < sh0) { sh0 = d0; p0 = i; }
      if (!sc1 && d1 < sh1) { sh1 = d1; p1 = i; }
      float m0 = sc0 ? BIGF : sh0;
      float m1 = sc1 ? BIGF : sh1;
      float mv = wave_min_all(fminf(m0, m1));
      unsigned long long bl0 = __ballot(m0 == mv);
      unsigned long long bl1 = __ballot(m1 == mv);
      int j0 = bl0 ? 2 * (int)__builtin_ctzll(bl0) : 0x7fffffff;
      int j1 = bl1 ? 2 * (int)__builtin_ctzll(bl1) + 1 : 0x7fffffff;
      int j = j0 < j1 ? j0 : j1;   // first-index tie-break
      minVal = mv;
      if (lane == (j >> 1)) { if (j & 1) sc1 = true; else sc0 = true; }
      int nxt = __builtin_amdgcn_readlane((j & 1) ? r41 : r40, j >> 1);
      if (nxt < 0) sink = j; else i = nxt;
    }

    // dual updates (before augmentation, scipy order)
    int jj = c4r < 0 ? 0 : c4r;
    float g0 = __shfl(sh0, jj >> 1);
    float g1 = __shfl(sh1, jj >> 1);
    float sj = (jj & 1) ? g1 : g0;
    if (lane < M_) {
      if (lane == cur) u_reg += minVal;
      else if ((srmask >> lane) & 1u) u_reg += minVal - sj;
    }
    if (sc0) v0 -= minVal - sh0;
    if (sc1) v1 -= minVal - sh1;

    // augment along path
    int j = sink;
    while (true) {
      int i2 = __builtin_amdgcn_readlane((j & 1) ? p1 : p0, j >> 1);
      if (lane == (j >> 1)) { if (j & 1) r41 = i2; else r40 = i2; }
      int tmp = __builtin_amdgcn_readlane(c4r, i2);
      if (lane == i2) c4r = j;
      if (i2 == cur) break;
      j = tmp;
    }
  }
  if (lane < M_) out[b * M_ + lane] = (float)c4r;
}

extern "C" void kernel_launch(void* const* d_in, const int* in_sizes, int n_in,
                              void* d_out, int out_size, void* d_ws, size_t ws_size,
                              hipStream_t stream)
{
  const float* obj  = (const float*)d_in[0];   // [8,128]
  const float* pred = (const float*)d_in[1];   // [8,128,65536]
  const float* gt   = (const float*)d_in[2];   // [8,32,65536]
  float* out = (float*)d_out;                  // cost 32768 || indices 256 (as float)

  // per-(kc,b) partial slabs — no atomics, no memset needed
  float* xg_part  = (float*)d_ws;                              // 32*8*128*32
  float* sg_part  = xg_part + (size_t)KCHUNKS * B_ * N_ * M_;
  float* sp_part  = sg_part + (size_t)KCHUNKS * B_ * N_ * M_;  // 32*8*128
  float* ss_part  = sp_part + (size_t)KCHUNKS * B_ * N_;
  float* gts_part = ss_part + (size_t)KCHUNKS * B_ * N_;       // 32*8*32

  cost_partial_kernel<<<dim3(KCHUNKS, 4, B_), 256, 0, stream>>>(
      pred, gt, xg_part, sg_part, sp_part, ss_part, gts_part);
  finalize_kernel<<<dim3(32768 / 128), 128, 0, stream>>>(
      obj, xg_part, sg_part, sp_part, ss_part, gts_part, out);
  lsap_kernel<<<dim3(B_), 64, 0, stream>>>(out, out + 32768);
}